// Round 5
// baseline (206.318 us; speedup 1.0000x reference)
//
#include <hip/hip_runtime.h>
#include <math.h>

static constexpr int Bq  = 8;
static constexpr int DIN = 1024;
static constexpr int TTT = 2048;
static constexpr int KCB = 8192;

static constexpr int NCHC = 32;    // chunks (phase-1 granularity), 256 codes each
static constexpr int NCHT = 256;   // tiles (candidate granularity), 32 codes each
static constexpr float E_BOUND = 2.5e-4f;  // >= 6x the analyzed approx error

// d_out layout (floats)
static constexpr size_t OUT_OFS  = 0;
static constexpr size_t LOSS_OFS = (size_t)Bq * DIN * TTT;      // 16777216 (16 zeros)
static constexpr size_t IDX_OFS  = LOSS_OFS + 16;               // 16777232 (B*T)
static constexpr size_t ZE_OFS   = IDX_OFS + (size_t)Bq * TTT;  // 16793616 (B*8*T)

// ws layout (float offsets)
static constexpr size_t WS_CBN   = 0;          // 8192*8 normalized codebook (fp32, exact path)
static constexpr size_t WS_C2    = 65536;      // 8192 0.5*||c_n||^2 (exact path)
static constexpr size_t WS_WT    = 73728;      // 1024*8 transposed w_in
static constexpr size_t WS_ENC   = 81920;      // 16384*8 z_e row-major [row][cd]
static constexpr size_t WS_FRAGH = 212992;     // bf16-hi fragments, ushort[8192*16]
static constexpr size_t WS_FRAGL = 278528;     // bf16-lo fragments
static constexpr size_t WS_PARTC = 344064;     // float[32][16384] approx chunk minima
static constexpr size_t WS_PARTT = 868352;     // float[256][16384] approx tile minima
static constexpr size_t WS_IDXI  = 5062656;    // 16384 ints

typedef __attribute__((ext_vector_type(8)))  short bf16x8;
typedef __attribute__((ext_vector_type(16))) float f32x16;

__device__ __forceinline__ unsigned short bf16_rn(float x) {
  unsigned u = __float_as_uint(x);
  unsigned r = (u + 0x7FFFu + ((u >> 16) & 1u)) >> 16;
  return (unsigned short)r;
}
__device__ __forceinline__ float bf16_to_f(unsigned short h) {
  return __uint_as_float(((unsigned)h) << 16);
}

// Shared helpers: the bit-identical fp32 DAG for the EXACT path (k2b).
__device__ __forceinline__ void load_enc_neg_norm(const float* __restrict__ ws,
                                                  int r, float4& ma, float4& mb) {
  const float4* ep = (const float4*)(ws + WS_ENC + (size_t)r * 8);
  float4 a = ep[0], c = ep[1];
  float n2 = 0.f;
  n2 = fmaf(a.x, a.x, n2); n2 = fmaf(a.y, a.y, n2);
  n2 = fmaf(a.z, a.z, n2); n2 = fmaf(a.w, a.w, n2);
  n2 = fmaf(c.x, c.x, n2); n2 = fmaf(c.y, c.y, n2);
  n2 = fmaf(c.z, c.z, n2); n2 = fmaf(c.w, c.w, n2);
  float dn = fmaxf(sqrtf(n2), 1e-12f);
  ma.x = -(a.x / dn); ma.y = -(a.y / dn);
  ma.z = -(a.z / dn); ma.w = -(a.w / dn);
  mb.x = -(c.x / dn); mb.y = -(c.y / dn);
  mb.z = -(c.z / dn); mb.w = -(c.w / dn);
}

__device__ __forceinline__ float score8(const float4& ma, const float4& mb,
                                        const float4& c0, const float4& c1, float cc) {
  // score = 0.5*||c_n||^2 - enc_n . c_n (monotone transform of reference dist)
  float s = fmaf(ma.x, c0.x, cc);
  s = fmaf(ma.y, c0.y, s); s = fmaf(ma.z, c0.z, s); s = fmaf(ma.w, c0.w, s);
  s = fmaf(mb.x, c1.x, s); s = fmaf(mb.y, c1.y, s);
  s = fmaf(mb.z, c1.z, s); s = fmaf(mb.w, c1.w, s);
  return s;
}

// ---------------- K0: normalize codebook, build bf16-split MFMA fragments,
// transpose w_in, zero losses ----------
// Fragment layout for v_mfma_f32_32x32x16_bf16 (gfx950 split-halves): lane l,
// elem j -> row/col = l&31, k = (l>>5)*4 + (j&3) + (j>>2)*8.
// Per code: lane c   (h=0): j0..3 = c_n dims 0..3, j4 (k=8)  = -cc, j5..7 = 0
//           lane c+32(h=1): j0..3 = c_n dims 4..7, j4..7 (k=12..15) = 0
__global__ __launch_bounds__(256) void k0_prep(
    const float* __restrict__ w_in, const float* __restrict__ codebook,
    float* __restrict__ ws, float* __restrict__ out)
{
  int tid = blockIdx.x * 256 + threadIdx.x;
  if (tid < KCB) {
    const float4* cp = (const float4*)(codebook + (size_t)tid * 8);
    float4 a = cp[0], b = cp[1];
    float v[8] = {a.x, a.y, a.z, a.w, b.x, b.y, b.z, b.w};
    float n2 = 0.f;
#pragma unroll
    for (int o = 0; o < 8; o++) n2 = fmaf(v[o], v[o], n2);
    float dn = fmaxf(sqrtf(n2), 1e-12f);
    float u[8];
    float s2 = 0.f;
#pragma unroll
    for (int o = 0; o < 8; o++) { u[o] = v[o] / dn; s2 = fmaf(u[o], u[o], s2); }
    float4* wp = (float4*)(ws + WS_CBN + (size_t)tid * 8);
    wp[0] = make_float4(u[0], u[1], u[2], u[3]);
    wp[1] = make_float4(u[4], u[5], u[6], u[7]);
    float cc = 0.5f * s2;
    ws[WS_C2 + tid] = cc;  // folded half-norm for score = 0.5*c2 - dot

    unsigned short h[8], l[8];
#pragma unroll
    for (int o = 0; o < 8; o++) {
      unsigned short hh = bf16_rn(u[o]);
      h[o] = hh;
      l[o] = bf16_rn(u[o] - bf16_to_f(hh));
    }
    unsigned short hcc = bf16_rn(-cc);
    unsigned short lcc = bf16_rn(-cc - bf16_to_f(hcc));

    int cgrp = tid >> 10;        // macro chunk (1024 codes)
    int tl   = (tid >> 5) & 31;  // tile within macro chunk
    int lcol = tid & 31;         // row within tile
    size_t fb = (size_t)cgrp * 16384 + (size_t)tl * 512;  // ushort units
    unsigned short* FH = (unsigned short*)(ws + WS_FRAGH);
    unsigned short* FL = (unsigned short*)(ws + WS_FRAGL);
    size_t p0 = fb + (size_t)lcol * 8;          // h=0 lane
    size_t p1 = fb + (size_t)(lcol + 32) * 8;   // h=1 lane
#pragma unroll
    for (int e = 0; e < 4; e++) {
      FH[p0 + e] = h[e];      FL[p0 + e] = l[e];
      FH[p1 + e] = h[4 + e];  FL[p1 + e] = l[4 + e];
      FH[p1 + 4 + e] = 0;     FL[p1 + 4 + e] = 0;
    }
    FH[p0 + 4] = hcc; FL[p0 + 4] = lcc;
    FH[p0 + 5] = 0; FH[p0 + 6] = 0; FH[p0 + 7] = 0;
    FL[p0 + 5] = 0; FL[p0 + 6] = 0; FL[p0 + 7] = 0;
  } else if (tid < KCB + DIN) {
    int d = tid - KCB;
#pragma unroll
    for (int o = 0; o < 8; o++) ws[WS_WT + (size_t)d * 8 + o] = w_in[(size_t)o * DIN + d];
  } else if (tid < KCB + DIN + 16) {
    out[LOSS_OFS + (tid - KCB - DIN)] = 0.f;  // commit_loss + codebook_loss zeros
  }
}

// ---------------- K1: z_e = w_in @ z + b_in  (HBM-bound, 64 MiB read) ----------
__global__ __launch_bounds__(512) void k1_proj_in(
    const float* __restrict__ z, const float* __restrict__ b_in,
    float* __restrict__ ws, float* __restrict__ out)
{
  __shared__ __align__(16) float lds[16384];  // 64 KB: wt staging, then partial[32][8][64]
  int tid = threadIdx.x;
  int bx = blockIdx.x;
  int b = bx >> 5;
  int t0 = (bx & 31) << 6;
  {
    const float4* src = (const float4*)(ws + WS_WT);
    float4* dst = (float4*)lds;
#pragma unroll
    for (int i = 0; i < 4; i++) dst[tid + 512 * i] = src[tid + 512 * i];
  }
  __syncthreads();
  int tt = tid & 15;
  int dg = tid >> 4;
  const float* zb = z + (size_t)b * DIN * TTT + t0 + (tt << 2);
  float4 acc[8];
#pragma unroll
  for (int o = 0; o < 8; o++) acc[o] = make_float4(0.f, 0.f, 0.f, 0.f);
  int dbase = dg << 5;
  const float4* wl = (const float4*)lds;
#pragma unroll 8
  for (int i = 0; i < 32; i++) {
    int d = dbase + i;
    float4 zv = *(const float4*)(zb + (size_t)d * TTT);
    float4 w0 = wl[d * 2 + 0];
    float4 w1 = wl[d * 2 + 1];
#define ACC1(o, wsc)                                    \
    acc[o].x = fmaf(wsc, zv.x, acc[o].x);               \
    acc[o].y = fmaf(wsc, zv.y, acc[o].y);               \
    acc[o].z = fmaf(wsc, zv.z, acc[o].z);               \
    acc[o].w = fmaf(wsc, zv.w, acc[o].w);
    ACC1(0, w0.x) ACC1(1, w0.y) ACC1(2, w0.z) ACC1(3, w0.w)
    ACC1(4, w1.x) ACC1(5, w1.y) ACC1(6, w1.z) ACC1(7, w1.w)
#undef ACC1
  }
  __syncthreads();
  {
    float4* pl = (float4*)lds;
#pragma unroll
    for (int o = 0; o < 8; o++) pl[dg * 128 + o * 16 + tt] = acc[o];
  }
  __syncthreads();
  int o = tid >> 6;
  int t = tid & 63;
  float s = 0.f;
#pragma unroll
  for (int g = 0; g < 32; g++) s += lds[g * 512 + o * 64 + t];
  s += b_in[o];
  out[ZE_OFS + ((size_t)b * 8 + o) * TTT + t0 + t] = s;
  ws[WS_ENC + ((size_t)(b * TTT + t0 + t)) * 8 + o] = s;
}

// ---------------- K2: approx VQ min-scan on the MFMA pipe (operand-swapped).
// grid 512 = rowgroups(64, 256 rows) x macrochunks(8, 1024 codes). block 512 =
// 8 waves, each owns 32 rows. Fragments LDS-staged once per block (64 KB).
// A = codes (from staged fragments), B = enc -> D[m][n] = code m . enc n - cc_m.
// Lane holds col n = enc row; per-lane 16 regs = 16 codes -> per-tile min is a
// register fmax tree + ONE shfl_xor(32) (no butterfly). Emits minima per tile
// (32 codes) and per chunk (256 codes), both coalesced.
__global__ __launch_bounds__(512) void k2_scan(float* __restrict__ ws)
{
  __shared__ __align__(16) unsigned short lh[16384];   // 32 KB hi fragments
  __shared__ __align__(16) unsigned short llo[16384];  // 32 KB lo fragments
  int tid = threadIdx.x;
  int rg = blockIdx.x >> 3;  // 64 rowgroups of 256 rows
  int ch = blockIdx.x & 7;   // 8 macro chunks of 1024 codes
  {
    const float4* srcH = (const float4*)(ws + WS_FRAGH) + (size_t)ch * 2048;
    const float4* srcL = (const float4*)(ws + WS_FRAGL) + (size_t)ch * 2048;
    float4* dH = (float4*)lh;
    float4* dL = (float4*)llo;
#pragma unroll
    for (int i = 0; i < 4; i++) {
      dH[tid + 512 * i] = srcH[tid + 512 * i];
      dL[tid + 512 * i] = srcL[tid + 512 * i];
    }
  }
  int lane = tid & 63;
  int wv = tid >> 6;
  int rowbase = rg * 256 + wv * 32;
  int row = rowbase + (lane & 31);
  int h = lane >> 5;

  // B operand (enc): lane l -> col n = l&31 (enc row), k = (l>>5)*4+(j&3)+(j>>2)*8.
  // h=0: j0..3 = dims0..3, j4 (k=8) = 1.0 (cc-fold); h=1: j0..3 = dims4..7, j4..7 = 0.
  bf16x8 eh, el;
#pragma unroll
  for (int o = 0; o < 8; o++) { eh[o] = 0; el[o] = 0; }
  {
    const float4* ep = (const float4*)(ws + WS_ENC + (size_t)row * 8);
    float4 a = ep[0], c = ep[1];
    float n2 = 0.f;
    n2 = fmaf(a.x, a.x, n2); n2 = fmaf(a.y, a.y, n2);
    n2 = fmaf(a.z, a.z, n2); n2 = fmaf(a.w, a.w, n2);
    n2 = fmaf(c.x, c.x, n2); n2 = fmaf(c.y, c.y, n2);
    n2 = fmaf(c.z, c.z, n2); n2 = fmaf(c.w, c.w, n2);
    float dn = fmaxf(sqrtf(n2), 1e-12f);
    float v[8] = {a.x / dn, a.y / dn, a.z / dn, a.w / dn,
                  c.x / dn, c.y / dn, c.z / dn, c.w / dn};
    int vb = h * 4;
#pragma unroll
    for (int o = 0; o < 4; o++) {
      unsigned short hh = bf16_rn(v[vb + o]);
      eh[o] = (short)hh;
      el[o] = (short)bf16_rn(v[vb + o] - bf16_to_f(hh));
    }
    if (h == 0) eh[4] = (short)0x3F80;  // B[k=8][n] = 1.0
  }
  __syncthreads();

  float cmin = 3.4e38f;
#define TILE_MIN(acc, dst) {                                                  \
    float x0 = fmaxf(acc[0], acc[1]),  x1 = fmaxf(acc[2], acc[3]);            \
    float x2 = fmaxf(acc[4], acc[5]),  x3 = fmaxf(acc[6], acc[7]);            \
    float x4 = fmaxf(acc[8], acc[9]),  x5 = fmaxf(acc[10], acc[11]);          \
    float x6 = fmaxf(acc[12], acc[13]), x7 = fmaxf(acc[14], acc[15]);         \
    x0 = fmaxf(x0, x1); x2 = fmaxf(x2, x3); x4 = fmaxf(x4, x5);               \
    x6 = fmaxf(x6, x7); x0 = fmaxf(x0, x2); x4 = fmaxf(x4, x6);               \
    x0 = fmaxf(x0, x4);                                                       \
    x0 = fmaxf(x0, __shfl_xor(x0, 32));                                       \
    dst = -x0; }

#pragma unroll 4
  for (int t2 = 0; t2 < 32; t2 += 2) {
    bf16x8 ah0 = *(const bf16x8*)(&lh[((size_t)t2 * 64 + lane) * 8]);
    bf16x8 al0 = *(const bf16x8*)(&llo[((size_t)t2 * 64 + lane) * 8]);
    bf16x8 ah1 = *(const bf16x8*)(&lh[((size_t)(t2 + 1) * 64 + lane) * 8]);
    bf16x8 al1 = *(const bf16x8*)(&llo[((size_t)(t2 + 1) * 64 + lane) * 8]);
    f32x16 acc0, acc1;
#pragma unroll
    for (int i = 0; i < 16; i++) { acc0[i] = 0.f; acc1[i] = 0.f; }
    acc0 = __builtin_amdgcn_mfma_f32_32x32x16_bf16(ah0, eh, acc0, 0, 0, 0);
    acc0 = __builtin_amdgcn_mfma_f32_32x32x16_bf16(ah0, el, acc0, 0, 0, 0);
    acc0 = __builtin_amdgcn_mfma_f32_32x32x16_bf16(al0, eh, acc0, 0, 0, 0);
    acc1 = __builtin_amdgcn_mfma_f32_32x32x16_bf16(ah1, eh, acc1, 0, 0, 0);
    acc1 = __builtin_amdgcn_mfma_f32_32x32x16_bf16(ah1, el, acc1, 0, 0, 0);
    acc1 = __builtin_amdgcn_mfma_f32_32x32x16_bf16(al1, eh, acc1, 0, 0, 0);
    float tmin0, tmin1;
    TILE_MIN(acc0, tmin0)
    TILE_MIN(acc1, tmin1)
    cmin = fminf(cmin, fminf(tmin0, tmin1));
    if (lane < 32) {
      ws[WS_PARTT + (size_t)(ch * 32 + t2) * 16384 + row] = tmin0;
      ws[WS_PARTT + (size_t)(ch * 32 + t2 + 1) * 16384 + row] = tmin1;
    }
  }
#undef TILE_MIN
  if (lane < 32) ws[WS_PARTC + (size_t)ch * 16384 + row] = cmin;
}

// ---------------- K2b: EXACT argmin from approx tile/chunk minima.
// 32 threads/row. m~ = min over 32 chunk minima; thr = m~ + 2E. Candidate
// chunks (approx <= thr): their sub checks 32 tile minima, rescanning candidate
// tiles (32 codes) with the exact fp32 DAG. Final (score, lowest-index) butterfly
// == reference first-min tie order. Post-check: exact best > thr (bound violated,
// e.g. wrong MFMA layout) -> full exact scan. Always correct.
__global__ __launch_bounds__(256) void k2b_argmin(float* __restrict__ ws, float* __restrict__ out)
{
  int gtid = blockIdx.x * 256 + threadIdx.x;
  int r = gtid >> 5;
  int sub = gtid & 31;
  float pc = ws[WS_PARTC + (size_t)sub * 16384 + r];
  float m = pc;
#pragma unroll
  for (int off = 1; off <= 16; off <<= 1) m = fminf(m, __shfl_xor(m, off));
  float thr = m + 2.0f * E_BOUND;

  float4 ma, mb;
  load_enc_neg_norm(ws, r, ma, mb);

  float best = 3.4e38f;
  int bi = 0x7fffffff;
  if (pc <= thr) {
    int tb = sub << 5;  // this chunk's first tile; chunk = tiles tb..tb+31
#pragma unroll 4
    for (int t = 0; t < 32; t++) {
      float pt = ws[WS_PARTT + (size_t)(tb + t) * 16384 + r];
      if (pt <= thr) {
        int base = (tb + t) << 5;  // 32-code tile, ascending
#pragma unroll 4
        for (int k = 0; k < 32; k++) {
          const float4* cp = (const float4*)(ws + WS_CBN + (size_t)(base + k) * 8);
          float4 c0 = cp[0], c1 = cp[1];
          float cc = ws[WS_C2 + base + k];
          float s = score8(ma, mb, c0, c1, cc);
          if (s < best) { best = s; bi = base + k; }
        }
      }
    }
  }
  float rbest = best;
  int rbi = bi;
#pragma unroll
  for (int off = 1; off <= 16; off <<= 1) {
    float os = __shfl_xor(rbest, off);
    int oi = __shfl_xor(rbi, off);
    if (os < rbest || (os == rbest && oi < rbi)) { rbest = os; rbi = oi; }
  }
  if (rbest > thr) {  // approx bound violated -> exact full scan (correct, slow)
    best = 3.4e38f; bi = 0x7fffffff;
    int base0 = sub << 8;
    for (int k = 0; k < 256; k++) {
      const float4* cp = (const float4*)(ws + WS_CBN + (size_t)(base0 + k) * 8);
      float4 c0 = cp[0], c1 = cp[1];
      float cc = ws[WS_C2 + base0 + k];
      float s = score8(ma, mb, c0, c1, cc);
      if (s < best) { best = s; bi = base0 + k; }
    }
    rbest = best; rbi = bi;
#pragma unroll
    for (int off = 1; off <= 16; off <<= 1) {
      float os = __shfl_xor(rbest, off);
      int oi = __shfl_xor(rbi, off);
      if (os < rbest || (os == rbest && oi < rbi)) { rbest = os; rbi = oi; }
    }
  }
  if (sub == 0) {
    out[IDX_OFS + r] = (float)rbi;
    ((int*)(ws + WS_IDXI))[r] = rbi;
  }
}

// ---------------- K3: out = w_out @ codebook[idx] + b_out (HBM write-bound) -----
__global__ __launch_bounds__(256) void k3_proj_out(
    const float* __restrict__ codebook, const float* __restrict__ w_out,
    const float* __restrict__ b_out, const float* __restrict__ ws,
    float* __restrict__ out)
{
  int bx = blockIdx.x;
  int b = bx >> 7;
  int th = (bx >> 6) & 1;
  int dt = bx & 63;
  int tid = threadIdx.x;
  int t = (th << 10) + (tid << 2);
  const int* idxp = (const int*)(ws + WS_IDXI);
  int4 id = *(const int4*)(idxp + b * TTT + t);
  const float4* cbp = (const float4*)codebook;
  float4 c00 = cbp[(size_t)id.x * 2], c01 = cbp[(size_t)id.x * 2 + 1];
  float4 c10 = cbp[(size_t)id.y * 2], c11 = cbp[(size_t)id.y * 2 + 1];
  float4 c20 = cbp[(size_t)id.z * 2], c21 = cbp[(size_t)id.z * 2 + 1];
  float4 c30 = cbp[(size_t)id.w * 2], c31 = cbp[(size_t)id.w * 2 + 1];
  int d0 = dt << 4;
#pragma unroll 4
  for (int dd = 0; dd < 16; dd++) {
    int d = d0 + dd;
    const float* wr = w_out + (size_t)d * 8;
    float w0 = wr[0], w1 = wr[1], w2 = wr[2], w3 = wr[3];
    float w4 = wr[4], w5 = wr[5], w6 = wr[6], w7 = wr[7];
    float bb = b_out[d];
#define DOT8(lo, hi)                                                          \
    fmaf(w7, hi.w, fmaf(w6, hi.z, fmaf(w5, hi.y, fmaf(w4, hi.x,              \
    fmaf(w3, lo.w, fmaf(w2, lo.z, fmaf(w1, lo.y, fmaf(w0, lo.x, bb))))))))
    float4 r;
    r.x = DOT8(c00, c01);
    r.y = DOT8(c10, c11);
    r.z = DOT8(c20, c21);
    r.w = DOT8(c30, c31);
#undef DOT8
    *(float4*)(out + OUT_OFS + ((size_t)b * DIN + d) * TTT + t) = r;
  }
}

extern "C" void kernel_launch(void* const* d_in, const int* in_sizes, int n_in,
                              void* d_out, int out_size, void* d_ws, size_t ws_size,
                              hipStream_t stream) {
  const float* z        = (const float*)d_in[0];
  const float* w_in     = (const float*)d_in[1];
  const float* b_in     = (const float*)d_in[2];
  const float* w_out    = (const float*)d_in[3];
  const float* b_out    = (const float*)d_in[4];
  const float* codebook = (const float*)d_in[5];
  float* out = (float*)d_out;
  float* ws  = (float*)d_ws;

  k0_prep<<<dim3(37), dim3(256), 0, stream>>>(w_in, codebook, ws, out);
  k1_proj_in<<<dim3(256), dim3(512), 0, stream>>>(z, b_in, ws, out);
  k2_scan<<<dim3(512), dim3(512), 0, stream>>>(ws);
  k2b_argmin<<<dim3(2048), dim3(256), 0, stream>>>(ws, out);
  k3_proj_out<<<dim3(1024), dim3(256), 0, stream>>>(codebook, w_out, b_out, ws, out);
}

// Round 6
// 163.027 us; speedup vs baseline: 1.2655x; 1.2655x over previous
//
#include <hip/hip_runtime.h>
#include <math.h>

static constexpr int Bq  = 8;
static constexpr int DIN = 1024;
static constexpr int TTT = 2048;
static constexpr int KCB = 8192;

static constexpr int NTIL = 256;   // tiles (candidate granularity), 32 codes each
static constexpr float E_BOUND = 2.5e-4f;  // >= 6x the analyzed approx error

// d_out layout (floats)
static constexpr size_t OUT_OFS  = 0;
static constexpr size_t LOSS_OFS = (size_t)Bq * DIN * TTT;      // 16777216 (16 zeros)
static constexpr size_t IDX_OFS  = LOSS_OFS + 16;               // 16777232 (B*T)
static constexpr size_t ZE_OFS   = IDX_OFS + (size_t)Bq * TTT;  // 16793616 (B*8*T)

// ws layout (float offsets)
static constexpr size_t WS_CBN   = 0;          // 8192*8 normalized codebook (fp32, exact path)
static constexpr size_t WS_C2    = 65536;      // 8192 0.5*||c_n||^2 (exact path)
static constexpr size_t WS_WT    = 73728;      // 1024*8 transposed w_in
static constexpr size_t WS_ENC   = 81920;      // 16384*8 z_e row-major [row][cd]
static constexpr size_t WS_FRAGH = 212992;     // bf16-hi fragments, ushort[8192*16]
static constexpr size_t WS_FRAGL = 278528;     // bf16-lo fragments
static constexpr size_t WS_PARTT = 344064;     // float[16384][256] approx tile minima (ROW-major!)
static constexpr size_t WS_IDXI  = WS_PARTT + (size_t)16384 * NTIL; // 16384 ints

typedef __attribute__((ext_vector_type(8)))  short bf16x8;
typedef __attribute__((ext_vector_type(16))) float f32x16;

__device__ __forceinline__ unsigned short bf16_rn(float x) {
  unsigned u = __float_as_uint(x);
  unsigned r = (u + 0x7FFFu + ((u >> 16) & 1u)) >> 16;
  return (unsigned short)r;
}
__device__ __forceinline__ float bf16_to_f(unsigned short h) {
  return __uint_as_float(((unsigned)h) << 16);
}

// Shared helpers: the bit-identical fp32 DAG for the EXACT path (k2b).
__device__ __forceinline__ void load_enc_neg_norm(const float* __restrict__ ws,
                                                  int r, float4& ma, float4& mb) {
  const float4* ep = (const float4*)(ws + WS_ENC + (size_t)r * 8);
  float4 a = ep[0], c = ep[1];
  float n2 = 0.f;
  n2 = fmaf(a.x, a.x, n2); n2 = fmaf(a.y, a.y, n2);
  n2 = fmaf(a.z, a.z, n2); n2 = fmaf(a.w, a.w, n2);
  n2 = fmaf(c.x, c.x, n2); n2 = fmaf(c.y, c.y, n2);
  n2 = fmaf(c.z, c.z, n2); n2 = fmaf(c.w, c.w, n2);
  float dn = fmaxf(sqrtf(n2), 1e-12f);
  ma.x = -(a.x / dn); ma.y = -(a.y / dn);
  ma.z = -(a.z / dn); ma.w = -(a.w / dn);
  mb.x = -(c.x / dn); mb.y = -(c.y / dn);
  mb.z = -(c.z / dn); mb.w = -(c.w / dn);
}

__device__ __forceinline__ float score8(const float4& ma, const float4& mb,
                                        const float4& c0, const float4& c1, float cc) {
  // score = 0.5*||c_n||^2 - enc_n . c_n (monotone transform of reference dist)
  float s = fmaf(ma.x, c0.x, cc);
  s = fmaf(ma.y, c0.y, s); s = fmaf(ma.z, c0.z, s); s = fmaf(ma.w, c0.w, s);
  s = fmaf(mb.x, c1.x, s); s = fmaf(mb.y, c1.y, s);
  s = fmaf(mb.z, c1.z, s); s = fmaf(mb.w, c1.w, s);
  return s;
}

// ---------------- K0: normalize codebook, build bf16-split MFMA fragments,
// transpose w_in, zero losses ----------
// Fragment positions (h = lane>>5, j = elem). The SAME (h,j) convention is used
// for A (codes) and B (enc) in k2, so the HW (h,j)->k bijection cancels in the
// dot product and the scores are layout-independent (requires only A/B symmetry).
// Per code: lane c   (h=0): j0..3 = c_n dims 0..3, j4 = -cc, j5..7 = 0
//           lane c+32(h=1): j0..3 = c_n dims 4..7, j4..7 = 0
__global__ __launch_bounds__(256) void k0_prep(
    const float* __restrict__ w_in, const float* __restrict__ codebook,
    float* __restrict__ ws, float* __restrict__ out)
{
  int tid = blockIdx.x * 256 + threadIdx.x;
  if (tid < KCB) {
    const float4* cp = (const float4*)(codebook + (size_t)tid * 8);
    float4 a = cp[0], b = cp[1];
    float v[8] = {a.x, a.y, a.z, a.w, b.x, b.y, b.z, b.w};
    float n2 = 0.f;
#pragma unroll
    for (int o = 0; o < 8; o++) n2 = fmaf(v[o], v[o], n2);
    float dn = fmaxf(sqrtf(n2), 1e-12f);
    float u[8];
    float s2 = 0.f;
#pragma unroll
    for (int o = 0; o < 8; o++) { u[o] = v[o] / dn; s2 = fmaf(u[o], u[o], s2); }
    float4* wp = (float4*)(ws + WS_CBN + (size_t)tid * 8);
    wp[0] = make_float4(u[0], u[1], u[2], u[3]);
    wp[1] = make_float4(u[4], u[5], u[6], u[7]);
    float cc = 0.5f * s2;
    ws[WS_C2 + tid] = cc;  // folded half-norm for score = 0.5*c2 - dot

    unsigned short h[8], l[8];
#pragma unroll
    for (int o = 0; o < 8; o++) {
      unsigned short hh = bf16_rn(u[o]);
      h[o] = hh;
      l[o] = bf16_rn(u[o] - bf16_to_f(hh));
    }
    unsigned short hcc = bf16_rn(-cc);
    unsigned short lcc = bf16_rn(-cc - bf16_to_f(hcc));

    int cgrp = tid >> 10;        // macro chunk (1024 codes)
    int tl   = (tid >> 5) & 31;  // tile within macro chunk
    int lcol = tid & 31;         // row within tile
    size_t fb = (size_t)cgrp * 16384 + (size_t)tl * 512;  // ushort units
    unsigned short* FH = (unsigned short*)(ws + WS_FRAGH);
    unsigned short* FL = (unsigned short*)(ws + WS_FRAGL);
    size_t p0 = fb + (size_t)lcol * 8;          // h=0 lane
    size_t p1 = fb + (size_t)(lcol + 32) * 8;   // h=1 lane
#pragma unroll
    for (int e = 0; e < 4; e++) {
      FH[p0 + e] = h[e];      FL[p0 + e] = l[e];
      FH[p1 + e] = h[4 + e];  FL[p1 + e] = l[4 + e];
      FH[p1 + 4 + e] = 0;     FL[p1 + 4 + e] = 0;
    }
    FH[p0 + 4] = hcc; FL[p0 + 4] = lcc;
    FH[p0 + 5] = 0; FH[p0 + 6] = 0; FH[p0 + 7] = 0;
    FL[p0 + 5] = 0; FL[p0 + 6] = 0; FL[p0 + 7] = 0;
  } else if (tid < KCB + DIN) {
    int d = tid - KCB;
#pragma unroll
    for (int o = 0; o < 8; o++) ws[WS_WT + (size_t)d * 8 + o] = w_in[(size_t)o * DIN + d];
  } else if (tid < KCB + DIN + 16) {
    out[LOSS_OFS + (tid - KCB - DIN)] = 0.f;  // commit_loss + codebook_loss zeros
  }
}

// ---------------- K1: z_e = w_in @ z + b_in  (HBM-bound, 64 MiB read) ----------
__global__ __launch_bounds__(512) void k1_proj_in(
    const float* __restrict__ z, const float* __restrict__ b_in,
    float* __restrict__ ws, float* __restrict__ out)
{
  __shared__ __align__(16) float lds[16384];  // 64 KB: wt staging, then partial[32][8][64]
  int tid = threadIdx.x;
  int bx = blockIdx.x;
  int b = bx >> 5;
  int t0 = (bx & 31) << 6;
  {
    const float4* src = (const float4*)(ws + WS_WT);
    float4* dst = (float4*)lds;
#pragma unroll
    for (int i = 0; i < 4; i++) dst[tid + 512 * i] = src[tid + 512 * i];
  }
  __syncthreads();
  int tt = tid & 15;
  int dg = tid >> 4;
  const float* zb = z + (size_t)b * DIN * TTT + t0 + (tt << 2);
  float4 acc[8];
#pragma unroll
  for (int o = 0; o < 8; o++) acc[o] = make_float4(0.f, 0.f, 0.f, 0.f);
  int dbase = dg << 5;
  const float4* wl = (const float4*)lds;
#pragma unroll 8
  for (int i = 0; i < 32; i++) {
    int d = dbase + i;
    float4 zv = *(const float4*)(zb + (size_t)d * TTT);
    float4 w0 = wl[d * 2 + 0];
    float4 w1 = wl[d * 2 + 1];
#define ACC1(o, wsc)                                    \
    acc[o].x = fmaf(wsc, zv.x, acc[o].x);               \
    acc[o].y = fmaf(wsc, zv.y, acc[o].y);               \
    acc[o].z = fmaf(wsc, zv.z, acc[o].z);               \
    acc[o].w = fmaf(wsc, zv.w, acc[o].w);
    ACC1(0, w0.x) ACC1(1, w0.y) ACC1(2, w0.z) ACC1(3, w0.w)
    ACC1(4, w1.x) ACC1(5, w1.y) ACC1(6, w1.z) ACC1(7, w1.w)
#undef ACC1
  }
  __syncthreads();
  {
    float4* pl = (float4*)lds;
#pragma unroll
    for (int o = 0; o < 8; o++) pl[dg * 128 + o * 16 + tt] = acc[o];
  }
  __syncthreads();
  int o = tid >> 6;
  int t = tid & 63;
  float s = 0.f;
#pragma unroll
  for (int g = 0; g < 32; g++) s += lds[g * 512 + o * 64 + t];
  s += b_in[o];
  out[ZE_OFS + ((size_t)b * 8 + o) * TTT + t0 + t] = s;
  ws[WS_ENC + ((size_t)(b * TTT + t0 + t)) * 8 + o] = s;
}

// ---------------- K2: approx VQ min-scan on the MFMA pipe (operand-swapped).
// grid 512 = rowgroups(64, 256 rows) x macrochunks(8, 1024 codes). block 512 =
// 8 waves, each owns 32 rows. Fragments LDS-staged once per block (64 KB).
// A = codes, B = enc -> D[m][n] = code m . enc n - cc_m. Lane holds enc row
// n = lane&31; 16 regs = 16 codes; tile min = reg fmax tree + 1 shfl_xor(32).
// Tile minima accumulate in registers (full unroll, static idx) and store
// [row][tile] row-major: 128 B contiguous per row = full cachelines, and k2b
// reads become fully coalesced.
__global__ __launch_bounds__(512) void k2_scan(float* __restrict__ ws)
{
  __shared__ __align__(16) unsigned short lh[16384];   // 32 KB hi fragments
  __shared__ __align__(16) unsigned short llo[16384];  // 32 KB lo fragments
  int tid = threadIdx.x;
  int rg = blockIdx.x >> 3;  // 64 rowgroups of 256 rows
  int ch = blockIdx.x & 7;   // 8 macro chunks of 1024 codes (32 tiles)
  {
    const float4* srcH = (const float4*)(ws + WS_FRAGH) + (size_t)ch * 2048;
    const float4* srcL = (const float4*)(ws + WS_FRAGL) + (size_t)ch * 2048;
    float4* dH = (float4*)lh;
    float4* dL = (float4*)llo;
#pragma unroll
    for (int i = 0; i < 4; i++) {
      dH[tid + 512 * i] = srcH[tid + 512 * i];
      dL[tid + 512 * i] = srcL[tid + 512 * i];
    }
  }
  int lane = tid & 63;
  int wv = tid >> 6;
  int rowbase = rg * 256 + wv * 32;
  int row = rowbase + (lane & 31);
  int h = lane >> 5;

  // B operand (enc): lane l -> col n = l&31 (enc row); positions (h,j) as in k0.
  bf16x8 eh, el;
#pragma unroll
  for (int o = 0; o < 8; o++) { eh[o] = 0; el[o] = 0; }
  {
    const float4* ep = (const float4*)(ws + WS_ENC + (size_t)row * 8);
    float4 a = ep[0], c = ep[1];
    float n2 = 0.f;
    n2 = fmaf(a.x, a.x, n2); n2 = fmaf(a.y, a.y, n2);
    n2 = fmaf(a.z, a.z, n2); n2 = fmaf(a.w, a.w, n2);
    n2 = fmaf(c.x, c.x, n2); n2 = fmaf(c.y, c.y, n2);
    n2 = fmaf(c.z, c.z, n2); n2 = fmaf(c.w, c.w, n2);
    float dn = fmaxf(sqrtf(n2), 1e-12f);
    float v[8] = {a.x / dn, a.y / dn, a.z / dn, a.w / dn,
                  c.x / dn, c.y / dn, c.z / dn, c.w / dn};
    int vb = h * 4;
#pragma unroll
    for (int o = 0; o < 4; o++) {
      unsigned short hh = bf16_rn(v[vb + o]);
      eh[o] = (short)hh;
      el[o] = (short)bf16_rn(v[vb + o] - bf16_to_f(hh));
    }
    if (h == 0) eh[4] = (short)0x3F80;  // cc-fold position j4 = 1.0
  }
  __syncthreads();

  float tm[32];
#define TILE_MIN(acc, dst) {                                                  \
    float x0 = fmaxf(acc[0], acc[1]),  x1 = fmaxf(acc[2], acc[3]);            \
    float x2 = fmaxf(acc[4], acc[5]),  x3 = fmaxf(acc[6], acc[7]);            \
    float x4 = fmaxf(acc[8], acc[9]),  x5 = fmaxf(acc[10], acc[11]);          \
    float x6 = fmaxf(acc[12], acc[13]), x7 = fmaxf(acc[14], acc[15]);         \
    x0 = fmaxf(x0, x1); x2 = fmaxf(x2, x3); x4 = fmaxf(x4, x5);               \
    x6 = fmaxf(x6, x7); x0 = fmaxf(x0, x2); x4 = fmaxf(x4, x6);               \
    x0 = fmaxf(x0, x4);                                                       \
    x0 = fmaxf(x0, __shfl_xor(x0, 32));                                       \
    dst = -x0; }

#pragma unroll
  for (int it = 0; it < 16; it++) {
    int t2 = it * 2;
    bf16x8 ah0 = *(const bf16x8*)(&lh[((size_t)t2 * 64 + lane) * 8]);
    bf16x8 al0 = *(const bf16x8*)(&llo[((size_t)t2 * 64 + lane) * 8]);
    bf16x8 ah1 = *(const bf16x8*)(&lh[((size_t)(t2 + 1) * 64 + lane) * 8]);
    bf16x8 al1 = *(const bf16x8*)(&llo[((size_t)(t2 + 1) * 64 + lane) * 8]);
    f32x16 acc0, acc1;
#pragma unroll
    for (int i = 0; i < 16; i++) { acc0[i] = 0.f; acc1[i] = 0.f; }
    acc0 = __builtin_amdgcn_mfma_f32_32x32x16_bf16(ah0, eh, acc0, 0, 0, 0);
    acc0 = __builtin_amdgcn_mfma_f32_32x32x16_bf16(ah0, el, acc0, 0, 0, 0);
    acc0 = __builtin_amdgcn_mfma_f32_32x32x16_bf16(al0, eh, acc0, 0, 0, 0);
    acc1 = __builtin_amdgcn_mfma_f32_32x32x16_bf16(ah1, eh, acc1, 0, 0, 0);
    acc1 = __builtin_amdgcn_mfma_f32_32x32x16_bf16(ah1, el, acc1, 0, 0, 0);
    acc1 = __builtin_amdgcn_mfma_f32_32x32x16_bf16(al1, eh, acc1, 0, 0, 0);
    TILE_MIN(acc0, tm[t2])
    TILE_MIN(acc1, tm[t2 + 1])
  }
#undef TILE_MIN
  if (lane < 32) {
    float4* d4 = (float4*)(ws + WS_PARTT + (size_t)row * NTIL + ch * 32);
    d4[0] = make_float4(tm[0], tm[1], tm[2], tm[3]);
    d4[1] = make_float4(tm[4], tm[5], tm[6], tm[7]);
    d4[2] = make_float4(tm[8], tm[9], tm[10], tm[11]);
    d4[3] = make_float4(tm[12], tm[13], tm[14], tm[15]);
    d4[4] = make_float4(tm[16], tm[17], tm[18], tm[19]);
    d4[5] = make_float4(tm[20], tm[21], tm[22], tm[23]);
    d4[6] = make_float4(tm[24], tm[25], tm[26], tm[27]);
    d4[7] = make_float4(tm[28], tm[29], tm[30], tm[31]);
  }
}

// ---------------- K2b: EXACT argmin from approx tile minima (row-major).
// 32 threads/row, 8 rows/block. Lane sub loads tiles [sub*8, sub*8+8) as 2x
// float4 (coalesced 1 KB/row). m~ = butterfly min over all 256 tile minima;
// thr = m~ + 2E. Candidate tiles processed COOPERATIVELY: ballot -> broadcast
// lowest candidate tile -> all 32 lanes score one code (coalesced codebook
// read) -> (score, lowest index) running min. Final butterfly == reference
// first-min tie order. Post-check fallback: cooperative strided full scan.
__global__ __launch_bounds__(256) void k2b_argmin(float* __restrict__ ws, float* __restrict__ out)
{
  int tid = threadIdx.x;
  int sub = tid & 31;           // lane within row-half
  int h = (tid >> 5) & 1;       // which half of the wave
  int r = blockIdx.x * 8 + (tid >> 5);

  const float4* tp = (const float4*)(ws + WS_PARTT + (size_t)r * NTIL + sub * 8);
  float4 t0 = tp[0], t1 = tp[1];
  float m = fminf(fminf(fminf(t0.x, t0.y), fminf(t0.z, t0.w)),
                  fminf(fminf(t1.x, t1.y), fminf(t1.z, t1.w)));
#pragma unroll
  for (int off = 1; off <= 16; off <<= 1) m = fminf(m, __shfl_xor(m, off));
  float thr = m + 2.0f * E_BOUND;

  unsigned mask = 0;
  if (t0.x <= thr) mask |= 1u;
  if (t0.y <= thr) mask |= 2u;
  if (t0.z <= thr) mask |= 4u;
  if (t0.w <= thr) mask |= 8u;
  if (t1.x <= thr) mask |= 16u;
  if (t1.y <= thr) mask |= 32u;
  if (t1.z <= thr) mask |= 64u;
  if (t1.w <= thr) mask |= 128u;

  float4 ma, mb;
  load_enc_neg_norm(ws, r, ma, mb);

  float best = 3.4e38f;
  int bi = 0x7fffffff;
  while (true) {
    unsigned long long b = __ballot(mask != 0);
    unsigned hm = (unsigned)(b >> (h * 32));
    if (hm == 0) break;
    int src = __ffs(hm) - 1;                        // lane-in-half with lowest tile
    int myt = sub * 8 + (__ffs(mask) - 1);          // valid only where mask != 0
    int tile = __shfl(myt, h * 32 + src);
    if (sub == src) mask &= mask - 1;
    int code = tile * 32 + sub;
    const float4* cp = (const float4*)(ws + WS_CBN + (size_t)code * 8);
    float4 c0 = cp[0], c1 = cp[1];
    float s = score8(ma, mb, c0, c1, ws[WS_C2 + code]);
    if (s < best || (s == best && code < bi)) { best = s; bi = code; }
  }
#pragma unroll
  for (int off = 1; off <= 16; off <<= 1) {
    float os = __shfl_xor(best, off);
    int oi = __shfl_xor(bi, off);
    if (os < best || (os == best && oi < bi)) { best = os; bi = oi; }
  }
  if (best > thr) {  // approx bound violated -> cooperative full exact scan
    best = 3.4e38f; bi = 0x7fffffff;
    for (int i = 0; i < 256; i++) {
      int code = i * 32 + sub;  // coalesced across lanes
      const float4* cp = (const float4*)(ws + WS_CBN + (size_t)code * 8);
      float4 c0 = cp[0], c1 = cp[1];
      float s = score8(ma, mb, c0, c1, ws[WS_C2 + code]);
      if (s < best || (s == best && code < bi)) { best = s; bi = code; }
    }
#pragma unroll
    for (int off = 1; off <= 16; off <<= 1) {
      float os = __shfl_xor(best, off);
      int oi = __shfl_xor(bi, off);
      if (os < best || (os == best && oi < bi)) { best = os; bi = oi; }
    }
  }
  if (sub == 0) {
    out[IDX_OFS + r] = (float)bi;
    ((int*)(ws + WS_IDXI))[r] = bi;
  }
}

// ---------------- K3: out = w_out @ codebook[idx] + b_out (HBM write-bound) -----
__global__ __launch_bounds__(256) void k3_proj_out(
    const float* __restrict__ codebook, const float* __restrict__ w_out,
    const float* __restrict__ b_out, const float* __restrict__ ws,
    float* __restrict__ out)
{
  int bx = blockIdx.x;
  int b = bx >> 7;
  int th = (bx >> 6) & 1;
  int dt = bx & 63;
  int tid = threadIdx.x;
  int t = (th << 10) + (tid << 2);
  const int* idxp = (const int*)(ws + WS_IDXI);
  int4 id = *(const int4*)(idxp + b * TTT + t);
  const float4* cbp = (const float4*)codebook;
  float4 c00 = cbp[(size_t)id.x * 2], c01 = cbp[(size_t)id.x * 2 + 1];
  float4 c10 = cbp[(size_t)id.y * 2], c11 = cbp[(size_t)id.y * 2 + 1];
  float4 c20 = cbp[(size_t)id.z * 2], c21 = cbp[(size_t)id.z * 2 + 1];
  float4 c30 = cbp[(size_t)id.w * 2], c31 = cbp[(size_t)id.w * 2 + 1];
  int d0 = dt << 4;
#pragma unroll 4
  for (int dd = 0; dd < 16; dd++) {
    int d = d0 + dd;
    const float* wr = w_out + (size_t)d * 8;
    float w0 = wr[0], w1 = wr[1], w2 = wr[2], w3 = wr[3];
    float w4 = wr[4], w5 = wr[5], w6 = wr[6], w7 = wr[7];
    float bb = b_out[d];
#define DOT8(lo, hi)                                                          \
    fmaf(w7, hi.w, fmaf(w6, hi.z, fmaf(w5, hi.y, fmaf(w4, hi.x,              \
    fmaf(w3, lo.w, fmaf(w2, lo.z, fmaf(w1, lo.y, fmaf(w0, lo.x, bb))))))))
    float4 r;
    r.x = DOT8(c00, c01);
    r.y = DOT8(c10, c11);
    r.z = DOT8(c20, c21);
    r.w = DOT8(c30, c31);
#undef DOT8
    *(float4*)(out + OUT_OFS + ((size_t)b * DIN + d) * TTT + t) = r;
  }
}

extern "C" void kernel_launch(void* const* d_in, const int* in_sizes, int n_in,
                              void* d_out, int out_size, void* d_ws, size_t ws_size,
                              hipStream_t stream) {
  const float* z        = (const float*)d_in[0];
  const float* w_in     = (const float*)d_in[1];
  const float* b_in     = (const float*)d_in[2];
  const float* w_out    = (const float*)d_in[3];
  const float* b_out    = (const float*)d_in[4];
  const float* codebook = (const float*)d_in[5];
  float* out = (float*)d_out;
  float* ws  = (float*)d_ws;

  k0_prep<<<dim3(37), dim3(256), 0, stream>>>(w_in, codebook, ws, out);
  k1_proj_in<<<dim3(256), dim3(512), 0, stream>>>(z, b_in, ws, out);
  k2_scan<<<dim3(512), dim3(512), 0, stream>>>(ws);
  k2b_argmin<<<dim3(2048), dim3(256), 0, stream>>>(ws, out);
  k3_proj_out<<<dim3(1024), dim3(256), 0, stream>>>(codebook, w_out, b_out, ws, out);
}